// Round 9
// baseline (198.359 us; speedup 1.0000x reference)
//
#include <hip/hip_runtime.h>
#include <hip/hip_bf16.h>

#define NN 50000
#define FF 64
#define EE 800000
#define CAP 64          // bucket capacity; max degree ~40 for Poisson(16)
#define NCHUNK 3125     // EE / 256
#define NB 8            // nodes per wave iteration (50000 = 8*6250, no tail)
#define PREP_BLOCKS 1563  // 1563*4 waves = 6252 >= 6250 node-groups: 1 group/wave

// Per-node matvecs: p[n]=(W1-W2)x[n]+b -> out (f32), xb[n]=W2 x[n] -> ws (bf16).
// NB=8 register blocking: weight columns read from LDS ONCE per 8 nodes
// (was: per node) -> DS instructions/node drop 128 -> 16. Prep was
// LDS-issue-bound (~60us); now bounded by VALU/VMEM (~15us).
__global__ __launch_bounds__(256, 4) void prep_kernel(
    const float* __restrict__ x, const float* __restrict__ W,
    const float* __restrict__ b, __hip_bfloat16* __restrict__ xbh,
    float* __restrict__ p, int* __restrict__ cursor)
{
    for (int i = blockIdx.x * 256 + threadIdx.x; i < NN; i += gridDim.x * 256)
        cursor[i] = 0;

    __shared__ float WA[64][65];   // W1-W2; +1 pad -> bank (lane+k)%32: 2-way, free
    __shared__ float W2s[64][65];
    __shared__ float bl[64];
    for (int i = threadIdx.x; i < 4096; i += 256) {
        int r = i >> 6, c = i & 63;
        float w2 = W[r * 128 + 64 + c];
        WA[r][c]  = W[r * 128 + c] - w2;
        W2s[r][c] = w2;
    }
    if (threadIdx.x < 64) bl[threadIdx.x] = b[threadIdx.x];
    __syncthreads();

    const int wid = threadIdx.x >> 6, lane = threadIdx.x & 63;
    const int stride = gridDim.x * 4 * NB;
    for (int n0 = (blockIdx.x * 4 + wid) * NB; n0 < NN; n0 += stride) {
        float a1[NB], a2[NB];
        #pragma unroll
        for (int t = 0; t < NB; ++t) { a1[t] = bl[lane]; a2[t] = 0.f; }

        const float4* xr0 = (const float4*)(x + (size_t)n0 * FF);
        #pragma unroll 4
        for (int kk = 0; kk < 16; ++kk) {
            // weight column chunk: read once, use for all NB nodes
            float wa0 = WA[lane][4*kk+0], wa1 = WA[lane][4*kk+1];
            float wa2 = WA[lane][4*kk+2], wa3 = WA[lane][4*kk+3];
            float w20 = W2s[lane][4*kk+0], w21 = W2s[lane][4*kk+1];
            float w22 = W2s[lane][4*kk+2], w23 = W2s[lane][4*kk+3];
            #pragma unroll
            for (int t = 0; t < NB; ++t) {
                float4 xk = xr0[t * 16 + kk];   // wave-uniform addr -> one 16B fetch
                a1[t] += wa0*xk.x + wa1*xk.y + wa2*xk.z + wa3*xk.w;
                a2[t] += w20*xk.x + w21*xk.y + w22*xk.z + w23*xk.w;
            }
        }
        #pragma unroll
        for (int t = 0; t < NB; ++t) {
            p  [(size_t)(n0 + t) * FF + lane] = a1[t];                   // + bias
            xbh[(size_t)(n0 + t) * FF + lane] = __float2bfloat16(a2[t]); // RNE
        }
    }
}

// XCD-partitioned bucket-fill: block bid handles only dsts with (dst&7)==bid&7.
// Round-robin block->XCD dispatch keeps each dst's bucket lines in ONE L2 ->
// full-line writebacks (kills the 16x write amplification seen in R5).
__global__ __launch_bounds__(256) void fill_kernel(const int* __restrict__ idx,
                                                   int* __restrict__ cursor,
                                                   int* __restrict__ ssrc) {
    int p     = blockIdx.x & 7;
    int chunk = blockIdx.x >> 3;
    int e = chunk * 256 + threadIdx.x;
    if (e >= EE) return;
    int dst = idx[EE + e];
    if ((dst & 7) != p) return;
    int src = idx[e];
    int pos = atomicAdd(&cursor[dst], 1);
    if (pos < CAP) ssrc[(dst << 6) + pos] = src;   // guard: memory safety only
}

// Gather: 8 threads per node, each owns 8 features (one uint4 = 8 bf16 / row).
// out[n] = c>0 ? p[n] + (sum_j xb[ssrc[n][j]])/c : 0   (p already in out)
__global__ __launch_bounds__(256) void aggregate_kernel(
    const ushort* __restrict__ xbh, const int* __restrict__ cursor,
    const int* __restrict__ ssrc, float* __restrict__ out)
{
    int tid = blockIdx.x * 256 + threadIdx.x;
    int n = tid >> 3;
    if (n >= NN) return;
    int q = tid & 7;                       // feature block: [q*8, q*8+8)
    int c = cursor[n];
    int cg = (c < CAP) ? c : CAP;
    const int* row = ssrc + ((size_t)n << 6);

    float s[8] = {0,0,0,0,0,0,0,0};
    // bf16 pair unpack: low = u<<16, high = u & 0xffff0000 (bit-exact)
    #define ACC(u)  do { \
        s[0] += __uint_as_float((u).x << 16); s[1] += __uint_as_float((u).x & 0xffff0000u); \
        s[2] += __uint_as_float((u).y << 16); s[3] += __uint_as_float((u).y & 0xffff0000u); \
        s[4] += __uint_as_float((u).z << 16); s[5] += __uint_as_float((u).z & 0xffff0000u); \
        s[6] += __uint_as_float((u).w << 16); s[7] += __uint_as_float((u).w & 0xffff0000u); } while (0)

    int j = 0;
    for (; j + 4 <= cg; j += 4) {
        int e0 = row[j], e1 = row[j+1], e2 = row[j+2], e3 = row[j+3];
        uint4 u0 = *(const uint4*)(xbh + (size_t)e0 * FF + q * 8);
        uint4 u1 = *(const uint4*)(xbh + (size_t)e1 * FF + q * 8);
        uint4 u2 = *(const uint4*)(xbh + (size_t)e2 * FF + q * 8);
        uint4 u3 = *(const uint4*)(xbh + (size_t)e3 * FF + q * 8);
        ACC(u0); ACC(u1); ACC(u2); ACC(u3);
    }
    for (; j < cg; ++j) {
        uint4 u = *(const uint4*)(xbh + (size_t)row[j] * FF + q * 8);
        ACC(u);
    }
    #undef ACC

    float* op = out + (size_t)n * FF + q * 8;
    if (c > 0) {
        float inv = 1.0f / (float)c;
        float4 p0 = *(const float4*)op;
        float4 p1 = *(const float4*)(op + 4);
        float4 r0, r1;
        r0.x = p0.x + s[0]*inv; r0.y = p0.y + s[1]*inv;
        r0.z = p0.z + s[2]*inv; r0.w = p0.w + s[3]*inv;
        r1.x = p1.x + s[4]*inv; r1.y = p1.y + s[5]*inv;
        r1.z = p1.z + s[6]*inv; r1.w = p1.w + s[7]*inv;
        *(float4*)op = r0;
        *(float4*)(op + 4) = r1;
    } else {
        float4 z = {0,0,0,0};
        *(float4*)op = z;
        *(float4*)(op + 4) = z;
    }
}

extern "C" void kernel_launch(void* const* d_in, const int* in_sizes, int n_in,
                              void* d_out, int out_size, void* d_ws, size_t ws_size,
                              hipStream_t stream) {
    const float* x   = (const float*)d_in[0];
    const int*   idx = (const int*)d_in[1];   // [2][E] int32
    const float* W   = (const float*)d_in[2]; // [64][128]
    const float* b   = (const float*)d_in[3]; // [64]
    float* out = (float*)d_out;               // prep writes p here; aggregate RMWs

    int*            cursor = (int*)d_ws;                  // [NN]
    int*            ssrc   = cursor + NN;                 // [NN][CAP]
    __hip_bfloat16* xbh    = (__hip_bfloat16*)(ssrc + (size_t)NN * CAP);  // [NN][FF]

    prep_kernel     <<<PREP_BLOCKS, 256, 0, stream>>>(x, W, b, xbh, out, cursor);
    fill_kernel     <<<NCHUNK * 8, 256, 0, stream>>>(idx, cursor, ssrc);
    aggregate_kernel<<<(NN * 8 + 255) / 256, 256, 0, stream>>>((const ushort*)xbh, cursor, ssrc, out);
}

// Round 10
// 163.591 us; speedup vs baseline: 1.2125x; 1.2125x over previous
//
#include <hip/hip_runtime.h>
#include <hip/hip_bf16.h>

#define NN 50000
#define FF 64
#define EE 800000
#define CAP 64          // bucket capacity; max degree ~40 for Poisson(16)
#define NCHUNK 3125     // EE / 256
#define NB 4            // nodes per wave iteration (50000 = 4*12500, no tail)

// Per-node matvecs: p[n]=(W1-W2)x[n]+b -> out (f32), xb[n]=W2 x[n] -> ws (bf16).
// NB=4 register blocking: weight cols read from LDS once per 4 nodes
// (DS/node 128 -> 32). NB=8+unroll4 (R9) spilled at VGPR=64 -> 90MB scratch
// traffic; NB=4+unroll2 keeps the live set ~90 VGPR, under the (256,4) cap.
__global__ __launch_bounds__(256, 4) void prep_kernel(
    const float* __restrict__ x, const float* __restrict__ W,
    const float* __restrict__ b, __hip_bfloat16* __restrict__ xbh,
    float* __restrict__ p, int* __restrict__ cursor)
{
    for (int i = blockIdx.x * 256 + threadIdx.x; i < NN; i += gridDim.x * 256)
        cursor[i] = 0;

    __shared__ float WA[64][65];   // W1-W2; +1 pad -> bank (lane+k)%32: 2-way, free
    __shared__ float W2s[64][65];
    __shared__ float bl[64];
    for (int i = threadIdx.x; i < 4096; i += 256) {
        int r = i >> 6, c = i & 63;
        float w2 = W[r * 128 + 64 + c];
        WA[r][c]  = W[r * 128 + c] - w2;
        W2s[r][c] = w2;
    }
    if (threadIdx.x < 64) bl[threadIdx.x] = b[threadIdx.x];
    __syncthreads();

    const int wid = threadIdx.x >> 6, lane = threadIdx.x & 63;
    const int stride = gridDim.x * 4 * NB;
    for (int n0 = (blockIdx.x * 4 + wid) * NB; n0 < NN; n0 += stride) {
        float a1[NB], a2[NB];
        #pragma unroll
        for (int t = 0; t < NB; ++t) { a1[t] = bl[lane]; a2[t] = 0.f; }

        const float4* xr0 = (const float4*)(x + (size_t)n0 * FF);
        #pragma unroll 2
        for (int kk = 0; kk < 16; ++kk) {
            // weight column chunk: read once, use for all NB nodes
            float wa0 = WA[lane][4*kk+0], wa1 = WA[lane][4*kk+1];
            float wa2 = WA[lane][4*kk+2], wa3 = WA[lane][4*kk+3];
            float w20 = W2s[lane][4*kk+0], w21 = W2s[lane][4*kk+1];
            float w22 = W2s[lane][4*kk+2], w23 = W2s[lane][4*kk+3];
            #pragma unroll
            for (int t = 0; t < NB; ++t) {
                float4 xk = xr0[t * 16 + kk];   // wave-uniform addr -> one 16B fetch
                a1[t] += wa0*xk.x + wa1*xk.y + wa2*xk.z + wa3*xk.w;
                a2[t] += w20*xk.x + w21*xk.y + w22*xk.z + w23*xk.w;
            }
        }
        #pragma unroll
        for (int t = 0; t < NB; ++t) {
            p  [(size_t)(n0 + t) * FF + lane] = a1[t];                   // + bias
            xbh[(size_t)(n0 + t) * FF + lane] = __float2bfloat16(a2[t]); // RNE
        }
    }
}

// XCD-partitioned bucket-fill: block bid handles only dsts with (dst&7)==bid&7.
// Round-robin block->XCD dispatch keeps each dst's bucket lines in ONE L2 ->
// full-line writebacks (kills the 16x write amplification seen in R5).
__global__ __launch_bounds__(256) void fill_kernel(const int* __restrict__ idx,
                                                   int* __restrict__ cursor,
                                                   int* __restrict__ ssrc) {
    int p     = blockIdx.x & 7;
    int chunk = blockIdx.x >> 3;
    int e = chunk * 256 + threadIdx.x;
    if (e >= EE) return;
    int dst = idx[EE + e];
    if ((dst & 7) != p) return;
    int src = idx[e];
    int pos = atomicAdd(&cursor[dst], 1);
    if (pos < CAP) ssrc[(dst << 6) + pos] = src;   // guard: memory safety only
}

// Gather: 8 threads per node, each owns 8 features (one uint4 = 8 bf16 / row).
// out[n] = c>0 ? p[n] + (sum_j xb[ssrc[n][j]])/c : 0   (p already in out)
__global__ __launch_bounds__(256) void aggregate_kernel(
    const ushort* __restrict__ xbh, const int* __restrict__ cursor,
    const int* __restrict__ ssrc, float* __restrict__ out)
{
    int tid = blockIdx.x * 256 + threadIdx.x;
    int n = tid >> 3;
    if (n >= NN) return;
    int q = tid & 7;                       // feature block: [q*8, q*8+8)
    int c = cursor[n];
    int cg = (c < CAP) ? c : CAP;
    const int* row = ssrc + ((size_t)n << 6);

    float s[8] = {0,0,0,0,0,0,0,0};
    // bf16 pair unpack: low = u<<16, high = u & 0xffff0000 (bit-exact)
    #define ACC(u)  do { \
        s[0] += __uint_as_float((u).x << 16); s[1] += __uint_as_float((u).x & 0xffff0000u); \
        s[2] += __uint_as_float((u).y << 16); s[3] += __uint_as_float((u).y & 0xffff0000u); \
        s[4] += __uint_as_float((u).z << 16); s[5] += __uint_as_float((u).z & 0xffff0000u); \
        s[6] += __uint_as_float((u).w << 16); s[7] += __uint_as_float((u).w & 0xffff0000u); } while (0)

    int j = 0;
    for (; j + 4 <= cg; j += 4) {
        int e0 = row[j], e1 = row[j+1], e2 = row[j+2], e3 = row[j+3];
        uint4 u0 = *(const uint4*)(xbh + (size_t)e0 * FF + q * 8);
        uint4 u1 = *(const uint4*)(xbh + (size_t)e1 * FF + q * 8);
        uint4 u2 = *(const uint4*)(xbh + (size_t)e2 * FF + q * 8);
        uint4 u3 = *(const uint4*)(xbh + (size_t)e3 * FF + q * 8);
        ACC(u0); ACC(u1); ACC(u2); ACC(u3);
    }
    for (; j < cg; ++j) {
        uint4 u = *(const uint4*)(xbh + (size_t)row[j] * FF + q * 8);
        ACC(u);
    }
    #undef ACC

    float* op = out + (size_t)n * FF + q * 8;
    if (c > 0) {
        float inv = 1.0f / (float)c;
        float4 p0 = *(const float4*)op;
        float4 p1 = *(const float4*)(op + 4);
        float4 r0, r1;
        r0.x = p0.x + s[0]*inv; r0.y = p0.y + s[1]*inv;
        r0.z = p0.z + s[2]*inv; r0.w = p0.w + s[3]*inv;
        r1.x = p1.x + s[4]*inv; r1.y = p1.y + s[5]*inv;
        r1.z = p1.z + s[6]*inv; r1.w = p1.w + s[7]*inv;
        *(float4*)op = r0;
        *(float4*)(op + 4) = r1;
    } else {
        float4 z = {0,0,0,0};
        *(float4*)op = z;
        *(float4*)(op + 4) = z;
    }
}

extern "C" void kernel_launch(void* const* d_in, const int* in_sizes, int n_in,
                              void* d_out, int out_size, void* d_ws, size_t ws_size,
                              hipStream_t stream) {
    const float* x   = (const float*)d_in[0];
    const int*   idx = (const int*)d_in[1];   // [2][E] int32
    const float* W   = (const float*)d_in[2]; // [64][128]
    const float* b   = (const float*)d_in[3]; // [64]
    float* out = (float*)d_out;               // prep writes p here; aggregate RMWs

    int*            cursor = (int*)d_ws;                  // [NN]
    int*            ssrc   = cursor + NN;                 // [NN][CAP]
    __hip_bfloat16* xbh    = (__hip_bfloat16*)(ssrc + (size_t)NN * CAP);  // [NN][FF]

    prep_kernel     <<<1024, 256, 0, stream>>>(x, W, b, xbh, out, cursor);
    fill_kernel     <<<NCHUNK * 8, 256, 0, stream>>>(idx, cursor, ssrc);
    aggregate_kernel<<<(NN * 8 + 255) / 256, 256, 0, stream>>>((const ushort*)xbh, cursor, ssrc, out);
}

// Round 11
// 160.843 us; speedup vs baseline: 1.2332x; 1.0171x over previous
//
#include <hip/hip_runtime.h>
#include <hip/hip_bf16.h>

#define NN 50000
#define FF 64
#define EE 800000
#define CAP 64          // bucket capacity; max degree ~40 for Poisson(16)
#define NCHUNK 3125     // EE / 256
#define NB 4            // nodes per wave iteration

// Per-node matvecs: p[n]=(W1-W2)x[n]+b -> out (f32), xb[n]=W2 x[n] -> ws (bf16).
// NB=4 register blocking (weight cols read once per 4 nodes: DS/node 128->32).
// waves_per_eu(2,4): R9/R10 showed launch_bounds(256,4) lets the allocator
// target 8 waves/EU -> 64 VGPR -> spills the ~90-VGPR live set to scratch
// (R9: 110MB phantom WRITE_SIZE). Capping max waves at 4 gives a 128-VGPR
// budget -> no spill; LDS 33KB still permits 4 blocks/CU.
__global__ __launch_bounds__(256)
__attribute__((amdgpu_waves_per_eu(2, 4)))
void prep_kernel(
    const float* __restrict__ x, const float* __restrict__ W,
    const float* __restrict__ b, __hip_bfloat16* __restrict__ xbh,
    float* __restrict__ p, int* __restrict__ cursor)
{
    for (int i = blockIdx.x * 256 + threadIdx.x; i < NN; i += gridDim.x * 256)
        cursor[i] = 0;

    __shared__ float WA[64][65];   // W1-W2; +1 pad -> bank (lane+k)%32: conflict-free b32
    __shared__ float W2s[64][65];
    __shared__ float bl[64];
    for (int i = threadIdx.x; i < 4096; i += 256) {
        int r = i >> 6, c = i & 63;
        float w2 = W[r * 128 + 64 + c];
        WA[r][c]  = W[r * 128 + c] - w2;
        W2s[r][c] = w2;
    }
    if (threadIdx.x < 64) bl[threadIdx.x] = b[threadIdx.x];
    __syncthreads();

    const int wid = threadIdx.x >> 6, lane = threadIdx.x & 63;
    const int stride = gridDim.x * 4 * NB;
    for (int n0 = (blockIdx.x * 4 + wid) * NB; n0 < NN; n0 += stride) {
        float a1[NB], a2[NB];
        #pragma unroll
        for (int t = 0; t < NB; ++t) { a1[t] = bl[lane]; a2[t] = 0.f; }

        const float4* xr0 = (const float4*)(x + (size_t)n0 * FF);
        #pragma unroll 2
        for (int kk = 0; kk < 16; ++kk) {
            // weight column chunk: read once, use for all NB nodes
            float wa0 = WA[lane][4*kk+0], wa1 = WA[lane][4*kk+1];
            float wa2 = WA[lane][4*kk+2], wa3 = WA[lane][4*kk+3];
            float w20 = W2s[lane][4*kk+0], w21 = W2s[lane][4*kk+1];
            float w22 = W2s[lane][4*kk+2], w23 = W2s[lane][4*kk+3];
            #pragma unroll
            for (int t = 0; t < NB; ++t) {
                float4 xk = xr0[t * 16 + kk];   // wave-uniform addr -> one 16B fetch
                a1[t] += wa0*xk.x + wa1*xk.y + wa2*xk.z + wa3*xk.w;
                a2[t] += w20*xk.x + w21*xk.y + w22*xk.z + w23*xk.w;
            }
        }
        #pragma unroll
        for (int t = 0; t < NB; ++t) {
            p  [(size_t)(n0 + t) * FF + lane] = a1[t];                   // + bias
            xbh[(size_t)(n0 + t) * FF + lane] = __float2bfloat16(a2[t]); // RNE
        }
    }
}

// XCD-partitioned bucket-fill: block bid handles only dsts with (dst&7)==bid&7.
// Round-robin block->XCD dispatch keeps each dst's bucket lines in ONE L2 ->
// full-line writebacks (kills the 16x write amplification seen in R5).
__global__ __launch_bounds__(256) void fill_kernel(const int* __restrict__ idx,
                                                   int* __restrict__ cursor,
                                                   int* __restrict__ ssrc) {
    int p     = blockIdx.x & 7;
    int chunk = blockIdx.x >> 3;
    int e = chunk * 256 + threadIdx.x;
    if (e >= EE) return;
    int dst = idx[EE + e];
    if ((dst & 7) != p) return;
    int src = idx[e];
    int pos = atomicAdd(&cursor[dst], 1);
    if (pos < CAP) ssrc[(dst << 6) + pos] = src;   // guard: memory safety only
}

// Gather: 8 threads per node, each owns 8 features (one uint4 = 8 bf16 / row).
// out[n] = c>0 ? p[n] + (sum_j xb[ssrc[n][j]])/c : 0   (p already in out)
__global__ __launch_bounds__(256) void aggregate_kernel(
    const ushort* __restrict__ xbh, const int* __restrict__ cursor,
    const int* __restrict__ ssrc, float* __restrict__ out)
{
    int tid = blockIdx.x * 256 + threadIdx.x;
    int n = tid >> 3;
    if (n >= NN) return;
    int q = tid & 7;                       // feature block: [q*8, q*8+8)
    int c = cursor[n];
    int cg = (c < CAP) ? c : CAP;
    const int* row = ssrc + ((size_t)n << 6);

    float s[8] = {0,0,0,0,0,0,0,0};
    // bf16 pair unpack: low = u<<16, high = u & 0xffff0000 (bit-exact)
    #define ACC(u)  do { \
        s[0] += __uint_as_float((u).x << 16); s[1] += __uint_as_float((u).x & 0xffff0000u); \
        s[2] += __uint_as_float((u).y << 16); s[3] += __uint_as_float((u).y & 0xffff0000u); \
        s[4] += __uint_as_float((u).z << 16); s[5] += __uint_as_float((u).z & 0xffff0000u); \
        s[6] += __uint_as_float((u).w << 16); s[7] += __uint_as_float((u).w & 0xffff0000u); } while (0)

    int j = 0;
    for (; j + 4 <= cg; j += 4) {
        int e0 = row[j], e1 = row[j+1], e2 = row[j+2], e3 = row[j+3];
        uint4 u0 = *(const uint4*)(xbh + (size_t)e0 * FF + q * 8);
        uint4 u1 = *(const uint4*)(xbh + (size_t)e1 * FF + q * 8);
        uint4 u2 = *(const uint4*)(xbh + (size_t)e2 * FF + q * 8);
        uint4 u3 = *(const uint4*)(xbh + (size_t)e3 * FF + q * 8);
        ACC(u0); ACC(u1); ACC(u2); ACC(u3);
    }
    for (; j < cg; ++j) {
        uint4 u = *(const uint4*)(xbh + (size_t)row[j] * FF + q * 8);
        ACC(u);
    }
    #undef ACC

    float* op = out + (size_t)n * FF + q * 8;
    if (c > 0) {
        float inv = 1.0f / (float)c;
        float4 p0 = *(const float4*)op;
        float4 p1 = *(const float4*)(op + 4);
        float4 r0, r1;
        r0.x = p0.x + s[0]*inv; r0.y = p0.y + s[1]*inv;
        r0.z = p0.z + s[2]*inv; r0.w = p0.w + s[3]*inv;
        r1.x = p1.x + s[4]*inv; r1.y = p1.y + s[5]*inv;
        r1.z = p1.z + s[6]*inv; r1.w = p1.w + s[7]*inv;
        *(float4*)op = r0;
        *(float4*)(op + 4) = r1;
    } else {
        float4 z = {0,0,0,0};
        *(float4*)op = z;
        *(float4*)(op + 4) = z;
    }
}

extern "C" void kernel_launch(void* const* d_in, const int* in_sizes, int n_in,
                              void* d_out, int out_size, void* d_ws, size_t ws_size,
                              hipStream_t stream) {
    const float* x   = (const float*)d_in[0];
    const int*   idx = (const int*)d_in[1];   // [2][E] int32
    const float* W   = (const float*)d_in[2]; // [64][128]
    const float* b   = (const float*)d_in[3]; // [64]
    float* out = (float*)d_out;               // prep writes p here; aggregate RMWs

    int*            cursor = (int*)d_ws;                  // [NN]
    int*            ssrc   = cursor + NN;                 // [NN][CAP]
    __hip_bfloat16* xbh    = (__hip_bfloat16*)(ssrc + (size_t)NN * CAP);  // [NN][FF]

    prep_kernel     <<<1024, 256, 0, stream>>>(x, W, b, xbh, out, cursor);
    fill_kernel     <<<NCHUNK * 8, 256, 0, stream>>>(idx, cursor, ssrc);
    aggregate_kernel<<<(NN * 8 + 255) / 256, 256, 0, stream>>>((const ushort*)xbh, cursor, ssrc, out);
}

// Round 12
// 142.618 us; speedup vs baseline: 1.3908x; 1.1278x over previous
//
#include <hip/hip_runtime.h>

#define NN 50000
#define FF 64
#define EE 800000
#define CAP 64          // bucket capacity; max degree ~40 for Poisson(16)
#define NCHUNK 3125     // EE / 256
#define NSTRIP 3125     // NN / 16 output strips for the MFMA GEMM

typedef short bf16x8 __attribute__((ext_vector_type(8)));
typedef float f32x4  __attribute__((ext_vector_type(4)));

// bf16 round-to-nearest-even (bit-exact with __float2bfloat16 on normals)
static __device__ __forceinline__ unsigned bf16rne(float f) {
    unsigned u = __float_as_uint(f);
    return (u + 0x7FFFu + ((u >> 16) & 1u)) >> 16;
}
static __device__ __forceinline__ unsigned packbf(float lo, float hi) {
    return bf16rne(lo) | (bf16rne(hi) << 16);
}

// K1: compress x -> xh (bf16), build Wcat = [W1-W2 | W2] (bf16 [64][128]),
// zero cursor. Pure streaming: no LDS, low VGPR.
__global__ __launch_bounds__(256) void prep_kernel(
    const float* __restrict__ x, const float* __restrict__ W,
    ushort* __restrict__ xh, ushort* __restrict__ wcat, int* __restrict__ cursor)
{
    int tid = blockIdx.x * 256 + threadIdx.x;
    int gs  = gridDim.x * 256;
    for (int i = tid; i < NN; i += gs) cursor[i] = 0;
    // Wcat: 64x128, packed 2 bf16 per uint (k even -> both halves same side of 64)
    for (int i = tid; i < 64 * 64; i += gs) {
        int f = i >> 6, k = (i & 63) * 2;
        float lo = (k < 64) ? (W[f * 128 + k]     - W[f * 128 + 64 + k])     : W[f * 128 + k];
        float hi = (k < 63) ? (W[f * 128 + k + 1] - W[f * 128 + 64 + k + 1]) : W[f * 128 + k + 1];
        ((unsigned*)wcat)[i] = packbf(lo, hi);
    }
    // x: 3.2M f32 -> 8 bf16 per thread-iter
    for (int i = tid; i < NN * FF / 8; i += gs) {
        const float4* xr = (const float4*)x + (size_t)i * 2;
        float4 v0 = xr[0], v1 = xr[1];
        uint4 o;
        o.x = packbf(v0.x, v0.y); o.y = packbf(v0.z, v0.w);
        o.z = packbf(v1.x, v1.y); o.w = packbf(v1.z, v1.w);
        ((uint4*)xh)[i] = o;
    }
}

// K2: XCD-partitioned bucket-fill (unchanged from R11): block bid handles only
// dsts with (dst&7)==bid&7 -> each dst's bucket lines dirty exactly one L2.
__global__ __launch_bounds__(256) void fill_kernel(const int* __restrict__ idx,
                                                   int* __restrict__ cursor,
                                                   int* __restrict__ ssrc) {
    int p     = blockIdx.x & 7;
    int chunk = blockIdx.x >> 3;
    int e = chunk * 256 + threadIdx.x;
    if (e >= EE) return;
    int dst = idx[EE + e];
    if ((dst & 7) != p) return;
    int src = idx[e];
    int pos = atomicAdd(&cursor[dst], 1);
    if (pos < CAP) ssrc[(dst << 6) + pos] = src;   // guard: memory safety only
}

// K3: gather-mean of raw xh rows: sh[n] = bf16( (sum_j xh[ssrc[n][j]]) / c ).
// 8 threads/node, uint4 = 8 bf16 per thread.
__global__ __launch_bounds__(256) void gather_kernel(
    const ushort* __restrict__ xh, const int* __restrict__ cursor,
    const int* __restrict__ ssrc, ushort* __restrict__ sh)
{
    int tid = blockIdx.x * 256 + threadIdx.x;
    int n = tid >> 3;
    if (n >= NN) return;
    int q = tid & 7;
    int c = cursor[n];
    int cg = (c < CAP) ? c : CAP;
    const int* row = ssrc + ((size_t)n << 6);

    float s[8] = {0,0,0,0,0,0,0,0};
    #define ACC(u)  do { \
        s[0] += __uint_as_float((u).x << 16); s[1] += __uint_as_float((u).x & 0xffff0000u); \
        s[2] += __uint_as_float((u).y << 16); s[3] += __uint_as_float((u).y & 0xffff0000u); \
        s[4] += __uint_as_float((u).z << 16); s[5] += __uint_as_float((u).z & 0xffff0000u); \
        s[6] += __uint_as_float((u).w << 16); s[7] += __uint_as_float((u).w & 0xffff0000u); } while (0)
    int j = 0;
    for (; j + 4 <= cg; j += 4) {
        int e0 = row[j], e1 = row[j+1], e2 = row[j+2], e3 = row[j+3];
        uint4 u0 = *(const uint4*)(xh + (size_t)e0 * FF + q * 8);
        uint4 u1 = *(const uint4*)(xh + (size_t)e1 * FF + q * 8);
        uint4 u2 = *(const uint4*)(xh + (size_t)e2 * FF + q * 8);
        uint4 u3 = *(const uint4*)(xh + (size_t)e3 * FF + q * 8);
        ACC(u0); ACC(u1); ACC(u2); ACC(u3);
    }
    for (; j < cg; ++j) {
        uint4 u = *(const uint4*)(xh + (size_t)row[j] * FF + q * 8);
        ACC(u);
    }
    #undef ACC

    float inv = (c > 0) ? 1.0f / (float)c : 0.0f;
    uint4 o;
    o.x = packbf(s[0]*inv, s[1]*inv); o.y = packbf(s[2]*inv, s[3]*inv);
    o.z = packbf(s[4]*inv, s[5]*inv); o.w = packbf(s[6]*inv, s[7]*inv);
    *(uint4*)(sh + (size_t)n * FF + q * 8) = o;
}

// K4: MFMA GEMM: out[n][f] = [xh[n] | sh[n]] . Wcat[f][:] + b[f]  (0 if c==0).
// One wave per 16-row strip; N=64 as 4 col-tiles; K=128 as 4 steps of 32.
// Layouts (mfma_f32_16x16x32_bf16): A: lane l holds A[l&15][(l>>4)*8+j];
// B: lane l holds B[(l>>4)*8+j][l&15]; D: col=lane&15, row=(lane>>4)*4+reg.
__global__ __launch_bounds__(256) void gemm_kernel(
    const ushort* __restrict__ xh, const ushort* __restrict__ sh,
    const ushort* __restrict__ wcat, const float* __restrict__ bias,
    const int* __restrict__ cursor, float* __restrict__ out)
{
    const int wid = threadIdx.x >> 6, lane = threadIdx.x & 63;
    const int r16 = lane & 15, g = lane >> 4;

    // B-fragments: loop-invariant. B[k][col] = Wcat[col][k] (Wcat row-major [64][128])
    bf16x8 bf[4][4];
    #pragma unroll
    for (int nt = 0; nt < 4; ++nt)
        #pragma unroll
        for (int ks = 0; ks < 4; ++ks)
            bf[nt][ks] = *(const bf16x8*)(wcat + (nt * 16 + r16) * 128 + ks * 32 + g * 8);
    float bv[4];
    #pragma unroll
    for (int nt = 0; nt < 4; ++nt) bv[nt] = bias[nt * 16 + r16];

    for (int strip = blockIdx.x * 4 + wid; strip < NSTRIP; strip += gridDim.x * 4) {
        int n0 = strip * 16;
        const ushort* ax = xh + (size_t)(n0 + r16) * FF + g * 8;
        const ushort* as = sh + (size_t)(n0 + r16) * FF + g * 8;
        bf16x8 a0 = *(const bf16x8*)(ax);        // k 0..31   (xh cols 0..31)
        bf16x8 a1 = *(const bf16x8*)(ax + 32);   // k 32..63  (xh cols 32..63)
        bf16x8 a2 = *(const bf16x8*)(as);        // k 64..95  (sh cols 0..31)
        bf16x8 a3 = *(const bf16x8*)(as + 32);   // k 96..127 (sh cols 32..63)

        f32x4 acc[4] = {{0,0,0,0},{0,0,0,0},{0,0,0,0},{0,0,0,0}};
        #pragma unroll
        for (int nt = 0; nt < 4; ++nt) {
            acc[nt] = __builtin_amdgcn_mfma_f32_16x16x32_bf16(a0, bf[nt][0], acc[nt], 0, 0, 0);
            acc[nt] = __builtin_amdgcn_mfma_f32_16x16x32_bf16(a1, bf[nt][1], acc[nt], 0, 0, 0);
            acc[nt] = __builtin_amdgcn_mfma_f32_16x16x32_bf16(a2, bf[nt][2], acc[nt], 0, 0, 0);
            acc[nt] = __builtin_amdgcn_mfma_f32_16x16x32_bf16(a3, bf[nt][3], acc[nt], 0, 0, 0);
        }

        int4 c4 = *(const int4*)(cursor + n0 + g * 4);
        int cc[4] = {c4.x, c4.y, c4.z, c4.w};
        #pragma unroll
        for (int r = 0; r < 4; ++r) {
            int n = n0 + g * 4 + r;
            float* op = out + (size_t)n * FF + r16;
            bool nz = cc[r] > 0;
            op[0]  = nz ? acc[0][r] + bv[0] : 0.f;
            op[16] = nz ? acc[1][r] + bv[1] : 0.f;
            op[32] = nz ? acc[2][r] + bv[2] : 0.f;
            op[48] = nz ? acc[3][r] + bv[3] : 0.f;
        }
    }
}

extern "C" void kernel_launch(void* const* d_in, const int* in_sizes, int n_in,
                              void* d_out, int out_size, void* d_ws, size_t ws_size,
                              hipStream_t stream) {
    const float* x   = (const float*)d_in[0];
    const int*   idx = (const int*)d_in[1];   // [2][E] int32
    const float* W   = (const float*)d_in[2]; // [64][128]
    const float* b   = (const float*)d_in[3]; // [64]
    float* out = (float*)d_out;

    int*    cursor = (int*)d_ws;                          // [NN]
    int*    ssrc   = cursor + NN;                         // [NN][CAP]
    ushort* xh     = (ushort*)(ssrc + (size_t)NN * CAP);  // [NN][FF] bf16
    ushort* sh     = xh + (size_t)NN * FF;                // [NN][FF] bf16
    ushort* wcat   = sh + (size_t)NN * FF;                // [64][128] bf16

    prep_kernel  <<<1563, 256, 0, stream>>>(x, W, xh, wcat, cursor);
    fill_kernel  <<<NCHUNK * 8, 256, 0, stream>>>(idx, cursor, ssrc);
    gather_kernel<<<(NN * 8 + 255) / 256, 256, 0, stream>>>(xh, cursor, ssrc, sh);
    gemm_kernel  <<<391, 256, 0, stream>>>(xh, sh, wcat, b, cursor, out);
}